// Round 1
// baseline (376.317 us; speedup 1.0000x reference)
//
#include <hip/hip_runtime.h>
#include <cstddef>

#define DEV static __device__ __forceinline__

typedef float f32x4 __attribute__((ext_vector_type(4)));
typedef __bf16 bf16x8 __attribute__((ext_vector_type(8)));
typedef unsigned short u16x8 __attribute__((ext_vector_type(8)));
typedef unsigned short u16x4 __attribute__((ext_vector_type(4)));
typedef _Float16 f16;
typedef _Float16 f16x4 __attribute__((ext_vector_type(4)));

// Problem constants (fixed shapes)
constexpr int BB = 2, LL = 2048, DM = 1024, NH = 16, DK = 64;

DEV unsigned short f2bf(float f) {
  unsigned u = __builtin_bit_cast(unsigned, f);
  u += 0x7fffu + ((u >> 16) & 1u);   // round-to-nearest-even
  return (unsigned short)(u >> 16);
}
DEV bf16x8 asbf(u16x8 v) { return __builtin_bit_cast(bf16x8, v); }
DEV f32x4 mfma16(u16x8 a, u16x8 b, f32x4 c) {
  return __builtin_amdgcn_mfma_f32_16x16x32_bf16(asbf(a), asbf(b), c, 0, 0, 0);
}

// ---------------------------------------------------------------------------
// prep_w: transpose+convert the 4 weight matrices (1024x1024 fp32, K-major)
// into bf16 W^T[N][K] so GEMM B-tiles stage with contiguous b128 reads.
// grid (32,32,4), block (32,8)
// ---------------------------------------------------------------------------
__global__ __launch_bounds__(256) void prep_w(const float* __restrict__ w0,
                                              const float* __restrict__ w1,
                                              const float* __restrict__ w2,
                                              const float* __restrict__ w3,
                                              unsigned short* __restrict__ wT) {
  __shared__ float tile[32][33];
  int z = blockIdx.z;
  const float* W = (z == 0) ? w0 : (z == 1) ? w1 : (z == 2) ? w2 : w3;
  unsigned short* out = wT + (size_t)z * DM * DM;
  int k0 = blockIdx.y * 32, n0 = blockIdx.x * 32;
  int tx = threadIdx.x, ty = threadIdx.y;
#pragma unroll
  for (int p = 0; p < 4; p++)
    tile[ty + 8 * p][tx] = W[(size_t)(k0 + ty + 8 * p) * DM + n0 + tx];
  __syncthreads();
#pragma unroll
  for (int p = 0; p < 4; p++)
    out[(size_t)(n0 + ty + 8 * p) * DM + k0 + tx] = f2bf(tile[tx][ty + 8 * p]);
}

// ---------------------------------------------------------------------------
// prep_bm: fused fp16 bias/mask: bm = (mask==0) ? -10000 : bias
// total elems 2*2048*2048 = 8388608; 4/thread; grid 8192 x 256
// ---------------------------------------------------------------------------
__global__ __launch_bounds__(256) void prep_bm(const int* __restrict__ mask,
                                               const float* __restrict__ bias,
                                               f16* __restrict__ bm) {
  size_t i = ((size_t)blockIdx.x * 256 + threadIdx.x) * 4;
  int4 mk = *(const int4*)(mask + i);
  float4 bs = *(const float4*)(bias + i);
  f16x4 o;
  o[0] = (f16)(mk.x == 0 ? -10000.f : bs.x);
  o[1] = (f16)(mk.y == 0 ? -10000.f : bs.y);
  o[2] = (f16)(mk.z == 0 ? -10000.f : bs.z);
  o[3] = (f16)(mk.w == 0 ? -10000.f : bs.w);
  *(f16x4*)(bm + i) = o;
}

// ---------------------------------------------------------------------------
// gemm128: C[4096x1024] = A[4096x1024] @ W (via W^T[1024][1024] bf16).
// 128x128 block tile, BK=64, 4 waves in 2x2, each wave 64x64 via 16x16x32 MFMA.
// AFP32: A is fp32 global, converted to bf16 during LDS staging.
// HEADS: write bf16 to head-split [B][H][L][64] with scale; else fp32 row-major.
// grid (8,32), block 256
// ---------------------------------------------------------------------------
template <bool AFP32, bool HEADS>
__global__ __launch_bounds__(256) void gemm128(const void* __restrict__ Aptr,
                                               const unsigned short* __restrict__ BT,
                                               void* __restrict__ Cptr, float scale) {
  __shared__ unsigned short Al[128][72];
  __shared__ unsigned short Bl[128][72];
  int t = threadIdx.x;
  int w = t >> 6, lane = t & 63, c = lane & 15, qd = lane >> 4;
  int wm = w >> 1, wn = w & 1;
  int m0 = blockIdx.y * 128, n0 = blockIdx.x * 128;
  f32x4 acc[4][4] = {};

  for (int k0 = 0; k0 < DM; k0 += 64) {
    __syncthreads();
    if (AFP32) {
      const float* A = (const float*)Aptr;
#pragma unroll
      for (int p = 0; p < 8; p++) {
        int ii = p * 256 + t;
        int m = ii >> 4, u = ii & 15;
        float4 v = *(const float4*)&A[(size_t)(m0 + m) * DM + k0 + 4 * u];
        u16x4 s;
        s[0] = f2bf(v.x); s[1] = f2bf(v.y); s[2] = f2bf(v.z); s[3] = f2bf(v.w);
        *(u16x4*)&Al[m][4 * u] = s;
      }
    } else {
      const unsigned short* A = (const unsigned short*)Aptr;
#pragma unroll
      for (int p = 0; p < 4; p++) {
        int ii = p * 256 + t;
        int m = ii >> 3, u = ii & 7;
        *(u16x8*)&Al[m][8 * u] = *(const u16x8*)&A[(size_t)(m0 + m) * DM + k0 + 8 * u];
      }
    }
#pragma unroll
    for (int p = 0; p < 4; p++) {
      int ii = p * 256 + t;
      int n = ii >> 3, u = ii & 7;
      *(u16x8*)&Bl[n][8 * u] = *(const u16x8*)&BT[(size_t)(n0 + n) * DM + k0 + 8 * u];
    }
    __syncthreads();
#pragma unroll
    for (int ks = 0; ks < 2; ks++) {
      u16x8 af[4], bf[4];
#pragma unroll
      for (int mt = 0; mt < 4; mt++)
        af[mt] = *(const u16x8*)&Al[64 * wm + 16 * mt + c][32 * ks + 8 * qd];
#pragma unroll
      for (int nt = 0; nt < 4; nt++)
        bf[nt] = *(const u16x8*)&Bl[64 * wn + 16 * nt + c][32 * ks + 8 * qd];
#pragma unroll
      for (int mt = 0; mt < 4; mt++)
#pragma unroll
        for (int nt = 0; nt < 4; nt++)
          acc[mt][nt] = mfma16(af[mt], bf[nt], acc[mt][nt]);
    }
  }

  if (HEADS) {
    unsigned short* Ch = (unsigned short*)Cptr;
#pragma unroll
    for (int mt = 0; mt < 4; mt++)
#pragma unroll
      for (int nt = 0; nt < 4; nt++)
#pragma unroll
        for (int i = 0; i < 4; i++) {
          int m = m0 + 64 * wm + 16 * mt + 4 * qd + i;   // row in [B*L]
          int n = n0 + 64 * wn + 16 * nt + c;            // col in [H*DK]
          int b = m >> 11, l = m & 2047, h = n >> 6, d = n & 63;
          Ch[(((size_t)b * NH + h) * LL + l) * DK + d] = f2bf(acc[mt][nt][i] * scale);
        }
  } else {
    float* C = (float*)Cptr;
#pragma unroll
    for (int mt = 0; mt < 4; mt++)
#pragma unroll
      for (int nt = 0; nt < 4; nt++)
#pragma unroll
        for (int i = 0; i < 4; i++) {
          int m = m0 + 64 * wm + 16 * mt + 4 * qd + i;
          int n = n0 + 64 * wn + 16 * nt + c;
          C[(size_t)m * DM + n] = acc[mt][nt][i];
        }
  }
}

// ---------------------------------------------------------------------------
// attn: flash-style, one block per (b, h, 128 q-rows); 4 waves x 32 q-rows.
// Computes S^T = K·Q^T (softmax reduction = 2 cross-quad shuffles; P^T lands
// in B-operand-friendly layout), online softmax fp32, O^T = V^T·P^T.
// TK = 64 per k-tile. qh is pre-scaled by 1/8.
// grid (H=16, L/128=16, B=2), block 256
// ---------------------------------------------------------------------------
__global__ __launch_bounds__(256) void attn_kern(const unsigned short* __restrict__ qh,
                                                 const unsigned short* __restrict__ kh,
                                                 const unsigned short* __restrict__ vh,
                                                 const f16* __restrict__ bm,
                                                 unsigned short* __restrict__ O) {
  __shared__ unsigned short Kl[64][72];     //  9216 B  K tile [key][d]
  __shared__ unsigned short Vt[64][72];     //  9216 B  V^T tile [d][key]
  __shared__ f16 Bml[128][72];              // 18432 B  bias/mask tile [q][key]
  __shared__ unsigned short Pl[4][32][72];  // 18432 B  per-wave P^T as [q][key]; aliased as Ql at start
  unsigned short(*Ql)[72] = reinterpret_cast<unsigned short(*)[72]>(&Pl[0][0][0]);  // [128][72]

  int t = threadIdx.x, w = t >> 6, lane = t & 63, c = lane & 15, qd = lane >> 4;
  int b = blockIdx.z, h = blockIdx.x, q0 = blockIdx.y * 128;
  const unsigned short* Q = qh + (((size_t)b * NH + h) * LL + q0) * DK;
  const unsigned short* K = kh + ((size_t)b * NH + h) * LL * DK;
  const unsigned short* V = vh + ((size_t)b * NH + h) * LL * DK;
  const f16* BMp = bm + ((size_t)b * LL + q0) * LL;

  // stage Q (128x64) once, hoist B-operand fragments into registers
#pragma unroll
  for (int p = 0; p < 4; p++) {
    int ii = p * 256 + t;
    int m = ii >> 3, u = ii & 7;
    *(u16x8*)&Ql[m][8 * u] = *(const u16x8*)&Q[(size_t)m * DK + 8 * u];
  }
  __syncthreads();
  u16x8 qf[2][2];  // [nt][ks]
#pragma unroll
  for (int nt = 0; nt < 2; nt++)
#pragma unroll
    for (int ks = 0; ks < 2; ks++)
      qf[nt][ks] = *(const u16x8*)&Ql[32 * w + 16 * nt + c][32 * ks + 8 * qd];

  float mi[2] = {-1e30f, -1e30f}, li[2] = {0.f, 0.f};
  f32x4 oacc[4][2] = {};  // [dt][nt]: d = 16*dt+4*qd+i, q = c

  for (int kt = 0; kt < LL; kt += 64) {
    __syncthreads();
    // stage K tile (64 keys x 64 d), direct
#pragma unroll
    for (int p = 0; p < 2; p++) {
      int ii = p * 256 + t;
      int m = ii >> 3, u = ii & 7;
      *(u16x8*)&Kl[m][8 * u] = *(const u16x8*)&K[(size_t)(kt + m) * DK + 8 * u];
    }
    // stage V tile transposed -> Vt[d][key]
    {
      int key = t & 63, seg = t >> 6;
#pragma unroll
      for (int u = 0; u < 2; u++) {
        u16x8 v8 = *(const u16x8*)&V[(size_t)(kt + key) * DK + 16 * seg + 8 * u];
#pragma unroll
        for (int j = 0; j < 8; j++) Vt[16 * seg + 8 * u + j][key] = v8[j];
      }
    }
    // stage bias/mask tile (128 q x 64 keys)
#pragma unroll
    for (int p = 0; p < 4; p++) {
      int ii = p * 256 + t;
      int q = ii >> 3, u = ii & 7;
      *(u16x8*)&Bml[q][8 * u] = *(const u16x8*)&BMp[(size_t)q * LL + kt + 8 * u];
    }
    __syncthreads();

    // S^T = K·Q^T : per wave tiles mt(key 0..3) x nt(q 0..1)
    f32x4 s[4][2];
#pragma unroll
    for (int mt = 0; mt < 4; mt++) {
      u16x8 k0f = *(const u16x8*)&Kl[16 * mt + c][8 * qd];
      u16x8 k1f = *(const u16x8*)&Kl[16 * mt + c][32 + 8 * qd];
#pragma unroll
      for (int nt = 0; nt < 2; nt++) {
        f32x4 z = {0.f, 0.f, 0.f, 0.f};
        f32x4 a = mfma16(k0f, qf[nt][0], z);
        s[mt][nt] = mfma16(k1f, qf[nt][1], a);
      }
    }
    // bias add + online softmax per q-row (row = c within quad group)
#pragma unroll
    for (int nt = 0; nt < 2; nt++) {
      float tm = -1e30f;
#pragma unroll
      for (int mt = 0; mt < 4; mt++) {
        f16x4 b4 = *(const f16x4*)&Bml[32 * w + 16 * nt + c][16 * mt + 4 * qd];
#pragma unroll
        for (int i = 0; i < 4; i++) {
          s[mt][nt][i] += (float)b4[i];
          tm = fmaxf(tm, s[mt][nt][i]);
        }
      }
      tm = fmaxf(tm, __shfl_xor(tm, 16));
      tm = fmaxf(tm, __shfl_xor(tm, 32));
      float mnew = fmaxf(mi[nt], tm);
      float alpha = __expf(mi[nt] - mnew);
      float ts = 0.f;
#pragma unroll
      for (int mt = 0; mt < 4; mt++)
#pragma unroll
        for (int i = 0; i < 4; i++) {
          float p = __expf(s[mt][nt][i] - mnew);
          s[mt][nt][i] = p;
          ts += p;
        }
      ts += __shfl_xor(ts, 16);
      ts += __shfl_xor(ts, 32);
      li[nt] = li[nt] * alpha + ts;
      mi[nt] = mnew;
#pragma unroll
      for (int dt = 0; dt < 4; dt++)
#pragma unroll
        for (int i = 0; i < 4; i++) oacc[dt][nt][i] *= alpha;
      // P^T -> LDS (wave-private region), [q][key] so PV B-frags read b128
#pragma unroll
      for (int mt = 0; mt < 4; mt++) {
        u16x4 pk;
#pragma unroll
        for (int i = 0; i < 4; i++) pk[i] = f2bf(s[mt][nt][i]);
        *(u16x4*)&Pl[w][16 * nt + c][16 * mt + 4 * qd] = pk;
      }
    }
    // O^T += V^T · P^T
    u16x8 pf[2][2];  // [nt][s4]
#pragma unroll
    for (int nt = 0; nt < 2; nt++)
#pragma unroll
      for (int s4 = 0; s4 < 2; s4++)
        pf[nt][s4] = *(const u16x8*)&Pl[w][16 * nt + c][32 * s4 + 8 * qd];
#pragma unroll
    for (int dt = 0; dt < 4; dt++) {
      u16x8 vf0 = *(const u16x8*)&Vt[16 * dt + c][8 * qd];
      u16x8 vf1 = *(const u16x8*)&Vt[16 * dt + c][32 + 8 * qd];
#pragma unroll
      for (int nt = 0; nt < 2; nt++) {
        oacc[dt][nt] = mfma16(vf0, pf[nt][0], oacc[dt][nt]);
        oacc[dt][nt] = mfma16(vf1, pf[nt][1], oacc[dt][nt]);
      }
    }
  }

  // epilogue: O[b][q][h*64+d] bf16 (row-major [B*L][1024] for the final GEMM)
#pragma unroll
  for (int nt = 0; nt < 2; nt++) {
    float rl = 1.f / li[nt];
    int q = q0 + 32 * w + 16 * nt + c;
#pragma unroll
    for (int dt = 0; dt < 4; dt++)
#pragma unroll
      for (int i = 0; i < 4; i++) {
        int d = 16 * dt + 4 * qd + i;
        O[((size_t)b * LL + q) * DM + h * DK + d] = f2bf(oacc[dt][nt][i] * rl);
      }
  }
}

// ---------------------------------------------------------------------------
extern "C" void kernel_launch(void* const* d_in, const int* in_sizes, int n_in,
                              void* d_out, int out_size, void* d_ws, size_t ws_size,
                              hipStream_t stream) {
  (void)in_sizes; (void)n_in; (void)out_size; (void)ws_size;
  const float* q = (const float*)d_in[0];
  const float* k = (const float*)d_in[1];
  const float* v = (const float*)d_in[2];
  const int* mask = (const int*)d_in[3];
  const float* bias = (const float*)d_in[4];
  const float* w_qs = (const float*)d_in[5];
  const float* w_ks = (const float*)d_in[6];
  const float* w_vs = (const float*)d_in[7];
  const float* w_fc = (const float*)d_in[8];

  char* ws = (char*)d_ws;
  size_t off = 0;
  unsigned short* wT = (unsigned short*)(ws + off); off += (size_t)4 * DM * DM * 2;     // 8 MiB
  unsigned short* qh = (unsigned short*)(ws + off); off += (size_t)BB * NH * LL * DK * 2;
  unsigned short* kh = (unsigned short*)(ws + off); off += (size_t)BB * NH * LL * DK * 2;
  unsigned short* vh = (unsigned short*)(ws + off); off += (size_t)BB * NH * LL * DK * 2;
  f16* bmw = (f16*)(ws + off);                      off += (size_t)BB * LL * LL * 2;    // 16 MiB
  unsigned short* Obuf = (unsigned short*)(ws + off); off += (size_t)BB * LL * DM * 2;  // 8 MiB
  // total 56 MiB

  prep_w<<<dim3(32, 32, 4), dim3(32, 8, 1), 0, stream>>>(w_qs, w_ks, w_vs, w_fc, wT);
  prep_bm<<<dim3(8192), dim3(256), 0, stream>>>(mask, bias, bmw);
  gemm128<true, true><<<dim3(8, 32), 256, 0, stream>>>(q, wT + (size_t)0 * DM * DM, qh, 0.125f);
  gemm128<true, true><<<dim3(8, 32), 256, 0, stream>>>(k, wT + (size_t)1 * DM * DM, kh, 1.0f);
  gemm128<true, true><<<dim3(8, 32), 256, 0, stream>>>(v, wT + (size_t)2 * DM * DM, vh, 1.0f);
  attn_kern<<<dim3(16, 16, 2), 256, 0, stream>>>(qh, kh, vh, bmw, Obuf);
  gemm128<false, false><<<dim3(8, 32), 256, 0, stream>>>(Obuf, wT + (size_t)3 * DM * DM,
                                                         (float*)d_out, 1.0f);
}

// Round 2
// 316.467 us; speedup vs baseline: 1.1891x; 1.1891x over previous
//
#include <hip/hip_runtime.h>
#include <cstddef>

#define DEV static __device__ __forceinline__

typedef float f32x4 __attribute__((ext_vector_type(4)));
typedef __bf16 bf16x8 __attribute__((ext_vector_type(8)));
typedef __bf16 bf16x4v __attribute__((ext_vector_type(4)));
typedef unsigned short u16x8 __attribute__((ext_vector_type(8)));
typedef unsigned short u16x4 __attribute__((ext_vector_type(4)));
typedef _Float16 f16;
typedef _Float16 f16x4 __attribute__((ext_vector_type(4)));

constexpr int BB = 2, LL = 2048, DM = 1024, NH = 16, DK = 64;
constexpr float LOG2E = 1.44269504f;

DEV unsigned short f2bf(float f) {
  unsigned u = __builtin_bit_cast(unsigned, f);
  u += 0x7fffu + ((u >> 16) & 1u);  // RNE
  return (unsigned short)(u >> 16);
}
DEV u16x4 cvt4(f32x4 v) {  // packed f32x4 -> bf16x4 (v_cvt_pk_bf16_f32)
  bf16x4v b = __builtin_convertvector(v, bf16x4v);
  return __builtin_bit_cast(u16x4, b);
}
DEV bf16x8 asbf(u16x8 v) { return __builtin_bit_cast(bf16x8, v); }
DEV f32x4 mfma16(u16x8 a, u16x8 b, f32x4 c) {
  return __builtin_amdgcn_mfma_f32_16x16x32_bf16(asbf(a), asbf(b), c, 0, 0, 0);
}
#if __has_builtin(__builtin_amdgcn_exp2f)
DEV float fexp2(float x) { return __builtin_amdgcn_exp2f(x); }
#else
DEV float fexp2(float x) { return exp2f(x); }
#endif
// async global->LDS, 16B per lane; ldsptr must be wave-uniform (HW adds lane*16)
DEV void g2lds16(const unsigned short* g, unsigned short* l) {
  __builtin_amdgcn_global_load_lds(
      (const __attribute__((address_space(1))) unsigned int*)g,
      (__attribute__((address_space(3))) unsigned int*)l, 16, 0, 0);
}

// ---------------------------------------------------------------------------
// prep_w: transpose+convert the 4 weight matrices (1024x1024 fp32, K-major)
// into bf16 W^T[N][K]. grid (32,32,4), block (32,8)
// ---------------------------------------------------------------------------
__global__ __launch_bounds__(256) void prep_w(const float* __restrict__ w0,
                                              const float* __restrict__ w1,
                                              const float* __restrict__ w2,
                                              const float* __restrict__ w3,
                                              unsigned short* __restrict__ wT) {
  __shared__ float tile[32][33];
  int z = blockIdx.z;
  const float* W = (z == 0) ? w0 : (z == 1) ? w1 : (z == 2) ? w2 : w3;
  unsigned short* out = wT + (size_t)z * DM * DM;
  int k0 = blockIdx.y * 32, n0 = blockIdx.x * 32;
  int tx = threadIdx.x, ty = threadIdx.y;
#pragma unroll
  for (int p = 0; p < 4; p++)
    tile[ty + 8 * p][tx] = W[(size_t)(k0 + ty + 8 * p) * DM + n0 + tx];
  __syncthreads();
#pragma unroll
  for (int p = 0; p < 4; p++)
    out[(size_t)(n0 + ty + 8 * p) * DM + k0 + tx] = f2bf(tile[tx][ty + 8 * p]);
}

// ---------------------------------------------------------------------------
// prep_bm: fused f16 bias/mask in exp2 domain: bm = (mask?bias:-1e4)*log2e
// ---------------------------------------------------------------------------
__global__ __launch_bounds__(256) void prep_bm(const int* __restrict__ mask,
                                               const float* __restrict__ bias,
                                               f16* __restrict__ bm) {
  size_t i = ((size_t)blockIdx.x * 256 + threadIdx.x) * 4;
  int4 mk = *(const int4*)(mask + i);
  float4 bs = *(const float4*)(bias + i);
  f16x4 o;
  o[0] = (f16)((mk.x == 0 ? -10000.f : bs.x) * LOG2E);
  o[1] = (f16)((mk.y == 0 ? -10000.f : bs.y) * LOG2E);
  o[2] = (f16)((mk.z == 0 ? -10000.f : bs.z) * LOG2E);
  o[3] = (f16)((mk.w == 0 ? -10000.f : bs.w) * LOG2E);
  *(f16x4*)(bm + i) = o;
}

// ---------------------------------------------------------------------------
// prep_cvt: fp32 -> bf16 for q,k,v activations. grid (2048,3), block 256
// ---------------------------------------------------------------------------
__global__ __launch_bounds__(256) void prep_cvt(const float* __restrict__ s0,
                                                const float* __restrict__ s1,
                                                const float* __restrict__ s2,
                                                unsigned short* __restrict__ dst) {
  int z = blockIdx.y;
  const float* src = (z == 0) ? s0 : (z == 1) ? s1 : s2;
  size_t i = ((size_t)blockIdx.x * 256 + threadIdx.x) * 8;
  float4 a = *(const float4*)(src + i);
  float4 b = *(const float4*)(src + i + 4);
  u16x8 o;
  o[0] = f2bf(a.x); o[1] = f2bf(a.y); o[2] = f2bf(a.z); o[3] = f2bf(a.w);
  o[4] = f2bf(b.x); o[5] = f2bf(b.y); o[6] = f2bf(b.z); o[7] = f2bf(b.w);
  *(u16x8*)(dst + (size_t)z * (size_t)(BB * LL) * DM + i) = o;
}

// ---------------------------------------------------------------------------
// gemm_bt: C[4096xDM] = A[4096xDM](bf16) @ W via W^T[N][K] bf16.
// 128x64 block tile, BK=64, 512 threads (8 waves as 4x2, wave tile 32x32).
// global_load_lds width-16 staging into XOR-swizzled unpadded LDS
// (column-group ^= row&7) -> conflict-free b128 fragment reads.
// grid (16, 32), block 512
// ---------------------------------------------------------------------------
enum { EP_HEADS = 0, EP_VT = 1, EP_F32 = 2 };

template <int EP>
__global__ __launch_bounds__(512) void gemm_bt(const unsigned short* __restrict__ A,
                                               const unsigned short* __restrict__ BT,
                                               void* __restrict__ Cptr, float scale) {
  __shared__ unsigned short Al[128 * 64];  // 16 KiB, swizzled
  __shared__ unsigned short Bl[64 * 64];   //  8 KiB, swizzled
  int t = threadIdx.x, w = t >> 6, lane = t & 63, c = lane & 15, qd = lane >> 4;
  int wm = w >> 1, wn = w & 1;
  int m0 = blockIdx.y * 128, n0 = blockIdx.x * 64;
  f32x4 acc[2][2] = {};

  for (int k0 = 0; k0 < DM; k0 += 64) {
    __syncthreads();
#pragma unroll
    for (int r = 0; r < 2; r++) {
      int f = r * 4096 + t * 8;
      int row = f >> 6, gg = (f >> 3) & 7;
      int sc = ((gg ^ (row & 7)) << 3);
      g2lds16(&A[(size_t)(m0 + row) * DM + k0 + sc], &Al[r * 4096 + w * 512]);
    }
    {
      int f = t * 8;
      int row = f >> 6, gg = (f >> 3) & 7;
      int sc = ((gg ^ (row & 7)) << 3);
      g2lds16(&BT[(size_t)(n0 + row) * DM + k0 + sc], &Bl[w * 512]);
    }
    __syncthreads();
#pragma unroll
    for (int ks = 0; ks < 2; ks++) {
      u16x8 af[2], bfr[2];
#pragma unroll
      for (int mt = 0; mt < 2; mt++) {
        int row = 32 * wm + 16 * mt + c;
        af[mt] = *(const u16x8*)&Al[row * 64 + (((4 * ks + qd) ^ (c & 7)) << 3)];
      }
#pragma unroll
      for (int nt = 0; nt < 2; nt++) {
        int row = 32 * wn + 16 * nt + c;
        bfr[nt] = *(const u16x8*)&Bl[row * 64 + (((4 * ks + qd) ^ (c & 7)) << 3)];
      }
#pragma unroll
      for (int mt = 0; mt < 2; mt++)
#pragma unroll
        for (int nt = 0; nt < 2; nt++)
          acc[mt][nt] = mfma16(af[mt], bfr[nt], acc[mt][nt]);
    }
  }

  int lm = 32 * wm + 4 * qd;  // + 16*mt + i gives m within block tile
  if (EP == EP_F32) {
    float* C = (float*)Cptr;
#pragma unroll
    for (int mt = 0; mt < 2; mt++)
#pragma unroll
      for (int nt = 0; nt < 2; nt++)
#pragma unroll
        for (int i = 0; i < 4; i++)
          C[(size_t)(m0 + lm + 16 * mt + i) * DM + n0 + 32 * wn + 16 * nt + c] =
              acc[mt][nt][i];
  } else if (EP == EP_VT) {  // per-head transposed: vT[b][h][d][l]
    unsigned short* Ch = (unsigned short*)Cptr;
#pragma unroll
    for (int mt = 0; mt < 2; mt++)
#pragma unroll
      for (int nt = 0; nt < 2; nt++) {
        int n = n0 + 32 * wn + 16 * nt + c;
        int h = n >> 6, d = n & 63;
        int m = m0 + lm + 16 * mt;  // i=0..3 consecutive in l
        int b = m >> 11, l = m & 2047;
        *(u16x4*)&Ch[(((size_t)b * NH + h) * DK + d) * LL + l] = cvt4(acc[mt][nt]);
      }
  } else {  // EP_HEADS: qh/kh[b][h][l][d], scaled bf16
    unsigned short* Ch = (unsigned short*)Cptr;
#pragma unroll
    for (int mt = 0; mt < 2; mt++)
#pragma unroll
      for (int nt = 0; nt < 2; nt++) {
        int n = n0 + 32 * wn + 16 * nt + c;
        int h = n >> 6, d = n & 63;
#pragma unroll
        for (int i = 0; i < 4; i++) {
          int m = m0 + lm + 16 * mt + i;
          int b = m >> 11, l = m & 2047;
          Ch[(((size_t)b * NH + h) * LL + l) * DK + d] = f2bf(acc[mt][nt][i] * scale);
        }
      }
  }
}

// ---------------------------------------------------------------------------
// attn: flash-style, 64 q-rows per block (grid 1024 -> 4 blocks/CU),
// 4 waves x 16 q-rows. S^T = K.Q^T, exp2-domain online softmax,
// O^T = V^T.P^T with V pre-transposed per head. Bias read direct from
// global (f16, prefetched one tile ahead). K/V/Q staged via global_load_lds
// into swizzled LDS. grid (16 h, 32 q0, 2 b), block 256
// ---------------------------------------------------------------------------
__global__ __launch_bounds__(256) void attn_kern(const unsigned short* __restrict__ qh,
                                                 const unsigned short* __restrict__ kh,
                                                 const unsigned short* __restrict__ vT,
                                                 const f16* __restrict__ bm,
                                                 unsigned short* __restrict__ O) {
  __shared__ unsigned short Kl[64 * 64];    // 8 KiB swizzled [key][d]
  __shared__ unsigned short Vt[64 * 64];    // 8 KiB swizzled [d][key]
  __shared__ unsigned short Pl[4][16][72];  // 9 KiB per-wave P^T [q][key]; aliases Ql
  unsigned short* Ql = &Pl[0][0][0];        // 4096 shorts needed <= 4608

  int t = threadIdx.x, w = t >> 6, lane = t & 63, c = lane & 15, qd = lane >> 4;
  int b = blockIdx.z, h = blockIdx.x, q0 = blockIdx.y * 64;
  const unsigned short* Q = qh + (((size_t)b * NH + h) * LL + q0) * DK;
  const unsigned short* K = kh + ((size_t)b * NH + h) * LL * DK;
  const unsigned short* V = vT + ((size_t)b * NH + h) * DK * LL;
  const f16* BM = bm + ((size_t)b * LL + q0 + 16 * w + c) * LL;  // this lane's q-row

  // stage Q (64x64) swizzled
#pragma unroll
  for (int r = 0; r < 2; r++) {
    int f = r * 2048 + t * 8;
    int row = f >> 6, gg = (f >> 3) & 7;
    g2lds16(&Q[(size_t)row * DK + (((gg ^ (row & 7)) << 3))], &Ql[r * 2048 + w * 512]);
  }
  __syncthreads();
  u16x8 qf[2];
#pragma unroll
  for (int ks = 0; ks < 2; ks++)
    qf[ks] = *(const u16x8*)&Ql[(16 * w + c) * 64 + (((4 * ks + qd) ^ (c & 7)) << 3)];

  float mi = -1e30f, li = 0.f;
  f32x4 oacc[4] = {};
  f16x4 b4[4];
#pragma unroll
  for (int mt = 0; mt < 4; mt++) b4[mt] = *(const f16x4*)&BM[16 * mt + 4 * qd];

  for (int kt = 0; kt < LL; kt += 64) {
    __syncthreads();  // protects Kl/Vt reuse and (iter 0) Ql->Pl alias
#pragma unroll
    for (int r = 0; r < 2; r++) {
      int f = r * 2048 + t * 8;
      int row = f >> 6, gg = (f >> 3) & 7;
      int sc = ((gg ^ (row & 7)) << 3);
      g2lds16(&K[(size_t)(kt + row) * DK + sc], &Kl[r * 2048 + w * 512]);
      g2lds16(&V[(size_t)row * LL + kt + sc], &Vt[r * 2048 + w * 512]);
    }
    // prefetch next tile's bias while staging is in flight
    int ktn = (kt + 64 < LL) ? kt + 64 : kt;
    f16x4 b4n[4];
#pragma unroll
    for (int mt = 0; mt < 4; mt++) b4n[mt] = *(const f16x4*)&BM[ktn + 16 * mt + 4 * qd];
    __syncthreads();

    // S^T = K.Q^T : D[m=key][n=q], lane holds q=c, keys 16mt+4qd+i
    f32x4 s[4];
#pragma unroll
    for (int mt = 0; mt < 4; mt++) {
      int row = 16 * mt + c;
      u16x8 k0f = *(const u16x8*)&Kl[row * 64 + (((0 + qd) ^ (c & 7)) << 3)];
      u16x8 k1f = *(const u16x8*)&Kl[row * 64 + (((4 + qd) ^ (c & 7)) << 3)];
      f32x4 z = {0.f, 0.f, 0.f, 0.f};
      z = mfma16(k0f, qf[0], z);
      s[mt] = mfma16(k1f, qf[1], z);
    }
    // exp2-domain online softmax (bias already has log2e folded)
    float tm = -1e30f;
#pragma unroll
    for (int mt = 0; mt < 4; mt++)
#pragma unroll
      for (int i = 0; i < 4; i++) {
        s[mt][i] += (float)b4[mt][i];
        tm = fmaxf(tm, s[mt][i]);
      }
    tm = fmaxf(tm, __shfl_xor(tm, 16));
    tm = fmaxf(tm, __shfl_xor(tm, 32));
    float mnew = fmaxf(mi, tm);
    float alpha = fexp2(mi - mnew);
    float ts = 0.f;
#pragma unroll
    for (int mt = 0; mt < 4; mt++) {
      f32x4 p;
#pragma unroll
      for (int i = 0; i < 4; i++) {
        p[i] = fexp2(s[mt][i] - mnew);
        ts += p[i];
      }
      *(u16x4*)&Pl[w][c][16 * mt + 4 * qd] = cvt4(p);  // wave-private, no barrier
    }
    ts += __shfl_xor(ts, 16);
    ts += __shfl_xor(ts, 32);
    li = li * alpha + ts;
    mi = mnew;
#pragma unroll
    for (int dt = 0; dt < 4; dt++) oacc[dt] *= alpha;

    // O^T += V^T.P^T : A = Vt (swizzled), B = P^T [q=c][key]
    u16x8 pf[2];
#pragma unroll
    for (int ks = 0; ks < 2; ks++)
      pf[ks] = *(const u16x8*)&Pl[w][c][32 * ks + 8 * qd];
#pragma unroll
    for (int dt = 0; dt < 4; dt++) {
      int row = 16 * dt + c;
      u16x8 v0f = *(const u16x8*)&Vt[row * 64 + (((0 + qd) ^ (c & 7)) << 3)];
      u16x8 v1f = *(const u16x8*)&Vt[row * 64 + (((4 + qd) ^ (c & 7)) << 3)];
      oacc[dt] = mfma16(v0f, pf[0], oacc[dt]);
      oacc[dt] = mfma16(v1f, pf[1], oacc[dt]);
    }
#pragma unroll
    for (int mt = 0; mt < 4; mt++) b4[mt] = b4n[mt];
  }

  // epilogue: O[b][q][h*64+d] bf16; lane: q=c(+16w+q0), d=16dt+4qd+i
  float rl = 1.f / li;
  size_t orow = ((size_t)b * LL + q0 + 16 * w + c) * DM + h * DK;
#pragma unroll
  for (int dt = 0; dt < 4; dt++)
    *(u16x4*)&O[orow + 16 * dt + 4 * qd] = cvt4(oacc[dt] * rl);
}

// ---------------------------------------------------------------------------
extern "C" void kernel_launch(void* const* d_in, const int* in_sizes, int n_in,
                              void* d_out, int out_size, void* d_ws, size_t ws_size,
                              hipStream_t stream) {
  (void)in_sizes; (void)n_in; (void)out_size; (void)ws_size;
  const float* q = (const float*)d_in[0];
  const float* k = (const float*)d_in[1];
  const float* v = (const float*)d_in[2];
  const int* mask = (const int*)d_in[3];
  const float* bias = (const float*)d_in[4];
  const float* w_qs = (const float*)d_in[5];
  const float* w_ks = (const float*)d_in[6];
  const float* w_vs = (const float*)d_in[7];
  const float* w_fc = (const float*)d_in[8];

  char* ws = (char*)d_ws;
  const size_t MB = 1024 * 1024;
  unsigned short* wT = (unsigned short*)(ws);            // [0,8M)
  f16* bmw = (f16*)(ws + 8 * MB);                        // [8,24M)
  unsigned short* qkvb = (unsigned short*)(ws + 24 * MB);  // qb/kb/vb [24,48M)
  unsigned short* qb = qkvb;
  unsigned short* kb = qkvb + (size_t)BB * LL * DM;
  unsigned short* vb = qkvb + (size_t)2 * BB * LL * DM;
  unsigned short* qh = (unsigned short*)(ws + 48 * MB);  // [48,56M)
  unsigned short* kh = (unsigned short*)(ws + 56 * MB);  // [56,64M)
  unsigned short* vhT = kb;   // aliases kb (dead after gemm_k)
  unsigned short* Obuf = qb;  // aliases qb (dead after gemm_q)
  // total 64 MiB

  prep_w<<<dim3(32, 32, 4), dim3(32, 8, 1), 0, stream>>>(w_qs, w_ks, w_vs, w_fc, wT);
  prep_bm<<<dim3(8192), dim3(256), 0, stream>>>(mask, bias, bmw);
  prep_cvt<<<dim3(2048, 3), dim3(256), 0, stream>>>(q, k, v, qkvb);
  // Q projection carries 1/sqrt(D_MODEL-head) temperature and log2e
  gemm_bt<EP_HEADS><<<dim3(16, 32), 512, 0, stream>>>(qb, wT + (size_t)0 * DM * DM, qh,
                                                      0.125f * LOG2E);
  gemm_bt<EP_HEADS><<<dim3(16, 32), 512, 0, stream>>>(kb, wT + (size_t)1 * DM * DM, kh, 1.0f);
  gemm_bt<EP_VT><<<dim3(16, 32), 512, 0, stream>>>(vb, wT + (size_t)2 * DM * DM, vhT, 1.0f);
  attn_kern<<<dim3(16, 32, 2), 256, 0, stream>>>(qh, kh, vhT, bmw, Obuf);
  gemm_bt<EP_F32><<<dim3(16, 32), 512, 0, stream>>>(Obuf, wT + (size_t)3 * DM * DM,
                                                    (float*)d_out, 1.0f);
}